// Round 2
// 1665.989 us; speedup vs baseline: 1.5506x; 1.5506x over previous
//
#include <hip/hip_runtime.h>
#include <hip/hip_bf16.h>

#define N_NODES 50000
#define N_EDGES 800000
#define HID     128
#define IMG_D   2048
#define TXT_D   768
#define NPB     8    // nodes per block in node_kernel
#define EPB     16   // edges per block in aggregate

typedef short          s16x8 __attribute__((ext_vector_type(8)));
typedef unsigned short u16x8 __attribute__((ext_vector_type(8)));
typedef unsigned short u16x4 __attribute__((ext_vector_type(4)));
typedef float          f32x4 __attribute__((ext_vector_type(4)));

// ---- fp32 -> bf16 (RNE) ----
static __device__ __forceinline__ unsigned short f2bf(float f) {
    unsigned int x = __float_as_uint(f);
    x += 0x7fffu + ((x >> 16) & 1u);
    return (unsigned short)(x >> 16);
}
struct BfPair { unsigned short h, l; };
// split a = hi + lo (both bf16), |a - hi - lo| ~ 2^-17 |a|
static __device__ __forceinline__ BfPair bsplit(float a) {
    BfPair p;
    p.h = f2bf(a);
    float hf = __uint_as_float((unsigned int)p.h << 16);
    p.l = f2bf(a - hf);
    return p;
}

static __device__ __forceinline__ f32x4 mfma16(s16x8 a, s16x8 b, f32x4 c) {
    return __builtin_amdgcn_mfma_f32_16x16x32_bf16(a, b, c, 0, 0, 0);
}

// ---------------- B prepack: fp32 [K x 128] -> bf16 hi/lo in MFMA fragment order ----------------
// Fragment (kf = k/32, nf = col/16): 64 lanes x 8 bf16 contiguous.
// lane l = 16*(krem/8) + (col%16); slot i = krem%8.
__global__ __launch_bounds__(256)
void prep_B(const float* __restrict__ B, unsigned short* __restrict__ Bhi,
            unsigned short* __restrict__ Blo, int K) {
    int idx = blockIdx.x * 256 + threadIdx.x;
    if (idx >= K * HID) return;
    int k = idx >> 7, col = idx & 127;
    int kf = k >> 5, kr = k & 31, b = kr >> 3, i = kr & 7;
    int nf = col >> 4, r = col & 15, l = (b << 4) | r;
    size_t o = ((((size_t)kf * 8 + nf) * 64) + l) * 8 + i;
    BfPair p = bsplit(B[(size_t)k * HID + col]);
    Bhi[o] = p.h; Blo[o] = p.l;
}

// ---------------- MFMA feature GEMM: C[M,128] = A[M,K] @ B[K,128] ----------------
// Block: 256 thr = 4 waves (2x2), BM=128, BN=128, BK=64. A reg-staged fp32->bf16(hi/lo)
// into XOR-swizzled LDS; B read prepacked from global (L2-resident).
// Split product: C = Ah@Bh + Al@Bh + Ah@Bl  (fp32-level accuracy).
template<int K>
__global__ __launch_bounds__(256, 2)
void feat_gemm_mfma(const float* __restrict__ A,
                    const unsigned short* __restrict__ Bhi,
                    const unsigned short* __restrict__ Blo,
                    float* __restrict__ C, int M) {
    __shared__ __align__(16) unsigned short sAhi[128][64];
    __shared__ __align__(16) unsigned short sAlo[128][64];

    const int tid  = threadIdx.x;
    const int lane = tid & 63;
    const int wid  = tid >> 6;
    const int wr   = wid >> 1;          // wave row (rows 64*wr .. +63)
    const int wc   = wid & 1;           // wave col (cols 64*wc .. +63)
    const int row0 = blockIdx.x * 128;

    f32x4 acc[4][4];
    #pragma unroll
    for (int m = 0; m < 4; ++m)
        #pragma unroll
        for (int n = 0; n < 4; ++n) acc[m][n] = f32x4{0.f, 0.f, 0.f, 0.f};

    for (int k0 = 0; k0 < K; k0 += 64) {
        // ---- stage A tile 128x64 fp32 -> bf16 hi/lo, swizzled ----
        #pragma unroll
        for (int it = 0; it < 8; ++it) {
            int chunk = tid + (it << 8);       // 0..2047 float4-chunks
            int r  = chunk >> 4;               // tile row
            int kc = chunk & 15;               // float4 index in row
            int gr = row0 + r; if (gr >= M) gr = M - 1;   // clamp (stores guarded)
            const float4 av = *(const float4*)&A[(size_t)gr * K + k0 + (kc << 2)];
            BfPair p0 = bsplit(av.x);
            BfPair p1 = bsplit(av.y);
            BfPair p2 = bsplit(av.z);
            BfPair p3 = bsplit(av.w);
            u16x4 h = {p0.h, p1.h, p2.h, p3.h};
            u16x4 l = {p0.l, p1.l, p2.l, p3.l};
            int e = (kc << 2) ^ ((r & 7) << 3);   // XOR swizzle (16B blocks)
            *(u16x4*)&sAhi[r][e] = h;
            *(u16x4*)&sAlo[r][e] = l;
        }
        __syncthreads();

        // ---- two K=32 sub-steps ----
        #pragma unroll
        for (int ks = 0; ks < 2; ++ks) {
            s16x8 ah[4], al[4], bh[4], bl[4];
            const int e0 = (ks << 5) | ((lane >> 4) << 3);
            #pragma unroll
            for (int m = 0; m < 4; ++m) {
                int r = (wr << 6) + (m << 4) + (lane & 15);
                int e = e0 ^ ((r & 7) << 3);
                ah[m] = __builtin_bit_cast(s16x8, *(const u16x8*)&sAhi[r][e]);
                al[m] = __builtin_bit_cast(s16x8, *(const u16x8*)&sAlo[r][e]);
            }
            const int kf = (k0 >> 5) + ks;
            #pragma unroll
            for (int n = 0; n < 4; ++n) {
                int nf = (wc << 2) + n;
                size_t fo = ((size_t)kf * 8 + nf) * 64 + lane;
                bh[n] = __builtin_bit_cast(s16x8, ((const u16x8*)Bhi)[fo]);
                bl[n] = __builtin_bit_cast(s16x8, ((const u16x8*)Blo)[fo]);
            }
            #pragma unroll
            for (int m = 0; m < 4; ++m)
                #pragma unroll
                for (int n = 0; n < 4; ++n) {
                    acc[m][n] = mfma16(ah[m], bh[n], acc[m][n]);
                    acc[m][n] = mfma16(al[m], bh[n], acc[m][n]);
                    acc[m][n] = mfma16(ah[m], bl[n], acc[m][n]);
                }
        }
        __syncthreads();
    }

    // ---- epilogue: D layout col=lane&15, row=4*(lane>>4)+j (m89-verified) ----
    const int crow = (wr << 6) + ((lane >> 4) << 2);
    const int ccol = (wc << 6) + (lane & 15);
    #pragma unroll
    for (int m = 0; m < 4; ++m)
        #pragma unroll
        for (int n = 0; n < 4; ++n)
            #pragma unroll
            for (int j = 0; j < 4; ++j) {
                int grow = row0 + crow + (m << 4) + j;
                if (grow < M) C[(size_t)grow * HID + ccol + (n << 4)] = acc[m][n][j];
            }
}

// ---------------- block-wide reduce of NPB values (128 threads) ----------------
static __device__ __forceinline__ void block_reduce_vec(float v[NPB], float* tmp) {
    int lane = threadIdx.x & 63;
    int wave = threadIdx.x >> 6;
    #pragma unroll
    for (int off = 32; off > 0; off >>= 1) {
        #pragma unroll
        for (int n = 0; n < NPB; ++n) v[n] += __shfl_xor(v[n], off, 64);
    }
    if (lane == 0) {
        #pragma unroll
        for (int n = 0; n < NPB; ++n) tmp[wave * NPB + n] = v[n];
    }
    __syncthreads();
    #pragma unroll
    for (int n = 0; n < NPB; ++n) v[n] = tmp[n] + tmp[NPB + n];
    __syncthreads();
}

// ---------------- gate MLP for NPB nodes at once ----------------
static __device__ __forceinline__ void gate_mlp_multi(
        const float (*sx)[2 * HID], float (*sh)[HID], float* tmp,
        const float* __restrict__ W1, const float* __restrict__ b1,
        const float* __restrict__ W2, const float* __restrict__ b2,
        const float* __restrict__ W3, const float* __restrict__ b3,
        float g[NPB]) {
    int j = threadIdx.x;
    float acc[NPB];
    float bb = b1[j];
    #pragma unroll
    for (int n = 0; n < NPB; ++n) acc[n] = bb;
    for (int i = 0; i < 2 * HID; i += 4) {
        float w0 = W1[(size_t)(i + 0) * HID + j];
        float w1 = W1[(size_t)(i + 1) * HID + j];
        float w2 = W1[(size_t)(i + 2) * HID + j];
        float w3 = W1[(size_t)(i + 3) * HID + j];
        #pragma unroll
        for (int n = 0; n < NPB; ++n) {
            const float4 xv = *(const float4*)&sx[n][i];
            acc[n] += xv.x * w0 + xv.y * w1 + xv.z * w2 + xv.w * w3;
        }
    }
    #pragma unroll
    for (int n = 0; n < NPB; ++n) sh[n][j] = fmaxf(acc[n], 0.f);
    __syncthreads();

    bb = b2[j];
    #pragma unroll
    for (int n = 0; n < NPB; ++n) acc[n] = bb;
    for (int i = 0; i < HID; i += 4) {
        float w0 = W2[(size_t)(i + 0) * HID + j];
        float w1 = W2[(size_t)(i + 1) * HID + j];
        float w2 = W2[(size_t)(i + 2) * HID + j];
        float w3 = W2[(size_t)(i + 3) * HID + j];
        #pragma unroll
        for (int n = 0; n < NPB; ++n) {
            const float4 xv = *(const float4*)&sh[n][i];
            acc[n] += xv.x * w0 + xv.y * w1 + xv.z * w2 + xv.w * w3;
        }
    }
    float w3v = W3[j], b3v = b3[0];
    #pragma unroll
    for (int n = 0; n < NPB; ++n) acc[n] = fmaxf(acc[n], 0.f) * w3v;
    block_reduce_vec(acc, tmp);
    #pragma unroll
    for (int n = 0; n < NPB; ++n) g[n] = 1.f / (1.f + expf(-(acc[n] + b3v)));
}

// ---------------- per-node fused kernel (NPB nodes / block) ----------------
__global__ __launch_bounds__(128)
void node_kernel(const int* __restrict__ node_id,
                 const float* __restrict__ emb_table,
                 const float* __restrict__ img_f_all,
                 const float* __restrict__ txt_f_all,
                 const float* __restrict__ iW1, const float* __restrict__ ib1,
                 const float* __restrict__ iW2, const float* __restrict__ ib2,
                 const float* __restrict__ iW3, const float* __restrict__ ib3,
                 const float* __restrict__ tW1, const float* __restrict__ tb1,
                 const float* __restrict__ tW2, const float* __restrict__ tb2,
                 const float* __restrict__ tW3, const float* __restrict__ tb3,
                 const float* __restrict__ combW, const float* __restrict__ combb,
                 const float* __restrict__ fcW, const float* __restrict__ attn,
                 float* __restrict__ z_out, float* __restrict__ e_src, float* __restrict__ e_dst) {
    __shared__ float sx[NPB][2 * HID];   // 8 KB
    __shared__ float sh[NPB][HID];       // 4 KB
    __shared__ float tmp[2 * NPB];
    int j = threadIdx.x;
    int n0 = blockIdx.x * NPB;

    float embed[NPB], imgf[NPB], txtf[NPB];
    #pragma unroll
    for (int n = 0; n < NPB; ++n) {
        int node = n0 + n;
        int nid = node_id[node];
        embed[n] = emb_table[(size_t)nid * HID + j];
        imgf[n]  = img_f_all[(size_t)node * HID + j];
        txtf[n]  = txt_f_all[(size_t)node * HID + j];
    }

    // ---- image gate ----
    #pragma unroll
    for (int n = 0; n < NPB; ++n) { sx[n][j] = embed[n]; sx[n][HID + j] = imgf[n]; }
    __syncthreads();
    float g[NPB];
    gate_mlp_multi(sx, sh, tmp, iW1, ib1, iW2, ib2, iW3, ib3, g);
    float img_v[NPB];
    #pragma unroll
    for (int n = 0; n < NPB; ++n) img_v[n] = g[n] * imgf[n] + (1.f - g[n]) * embed[n];

    // ---- text gate ----  (gate_mlp_multi ends with a barrier; sx rewrite safe)
    #pragma unroll
    for (int n = 0; n < NPB; ++n) { sx[n][j] = embed[n]; sx[n][HID + j] = txtf[n]; }
    __syncthreads();
    gate_mlp_multi(sx, sh, tmp, tW1, tb1, tW2, tb2, tW3, tb3, g);
    float txt_v[NPB];
    #pragma unroll
    for (int n = 0; n < NPB; ++n) txt_v[n] = g[n] * txtf[n] + (1.f - g[n]) * embed[n];

    // ---- combine (linear gate, no sigmoid) ----
    #pragma unroll
    for (int n = 0; n < NPB; ++n) { sx[n][j] = img_v[n]; sx[n][HID + j] = txt_v[n]; }
    __syncthreads();
    float acc[NPB];
    float bb = combb[j];
    #pragma unroll
    for (int n = 0; n < NPB; ++n) acc[n] = bb;
    for (int i = 0; i < 2 * HID; i += 4) {
        float w0 = combW[(size_t)(i + 0) * HID + j];
        float w1 = combW[(size_t)(i + 1) * HID + j];
        float w2 = combW[(size_t)(i + 2) * HID + j];
        float w3 = combW[(size_t)(i + 3) * HID + j];
        #pragma unroll
        for (int n = 0; n < NPB; ++n) {
            const float4 xv = *(const float4*)&sx[n][i];
            acc[n] += xv.x * w0 + xv.y * w1 + xv.z * w2 + xv.w * w3;
        }
    }
    float hcur[NPB];
    #pragma unroll
    for (int n = 0; n < NPB; ++n) hcur[n] = acc[n] * img_v[n] + (1.f - acc[n]) * txt_v[n];
    __syncthreads();
    #pragma unroll
    for (int n = 0; n < NPB; ++n) sh[n][j] = hcur[n];
    __syncthreads();

    // ---- fc: z = h @ fc_W ----
    #pragma unroll
    for (int n = 0; n < NPB; ++n) acc[n] = 0.f;
    for (int i = 0; i < HID; i += 4) {
        float w0 = fcW[(size_t)(i + 0) * HID + j];
        float w1 = fcW[(size_t)(i + 1) * HID + j];
        float w2 = fcW[(size_t)(i + 2) * HID + j];
        float w3 = fcW[(size_t)(i + 3) * HID + j];
        #pragma unroll
        for (int n = 0; n < NPB; ++n) {
            const float4 xv = *(const float4*)&sh[n][i];
            acc[n] += xv.x * w0 + xv.y * w1 + xv.z * w2 + xv.w * w3;
        }
    }
    #pragma unroll
    for (int n = 0; n < NPB; ++n)
        z_out[(size_t)(n0 + n) * HID + j] = acc[n];

    // ---- e_src / e_dst ----
    float a1 = attn[j], a2 = attn[HID + j];
    float v1[NPB], v2[NPB];
    #pragma unroll
    for (int n = 0; n < NPB; ++n) { v1[n] = acc[n] * a1; v2[n] = acc[n] * a2; }
    block_reduce_vec(v1, tmp);
    block_reduce_vec(v2, tmp);
    if (j == 0) {
        #pragma unroll
        for (int n = 0; n < NPB; ++n) { e_src[n0 + n] = v1[n]; e_dst[n0 + n] = v2[n]; }
    }
}

// ---------------- edge phase 1: exp(e) + denom ----------------
__global__ __launch_bounds__(256)
void edge_softmax_pre(const int* __restrict__ src, const int* __restrict__ dst,
                      const float* __restrict__ e_src, const float* __restrict__ e_dst,
                      float* __restrict__ exbuf, float* __restrict__ denom) {
    int k = blockIdx.x * 256 + threadIdx.x;
    if (k >= N_EDGES) return;
    float e = e_src[src[k]] + e_dst[dst[k]];
    e = (e >= 0.f) ? e : 0.01f * e;   // leaky_relu(0.01)
    // softmax is shift-invariant: skip segment_max; e is O(0.1) so exp is safe
    float ex = expf(e);
    exbuf[k] = ex;
    atomicAdd(&denom[dst[k]], ex);
}

// ---------------- edge phase 2: weighted aggregation into d_out (f32) ----------------
__global__ __launch_bounds__(128)
void edge_aggregate(const int* __restrict__ src, const int* __restrict__ dst,
                    const float* __restrict__ exbuf, const float* __restrict__ denom,
                    const float* __restrict__ z, float* __restrict__ hout) {
    int j = threadIdx.x;
    int base = blockIdx.x * EPB;
    int end = base + EPB;
    if (end > N_EDGES) end = N_EDGES;
    for (int k = base; k < end; ++k) {
        int d = dst[k], s = src[k];
        float alpha = exbuf[k] / fmaxf(denom[d], 1e-20f);
        atomicAdd(&hout[(size_t)d * HID + j], alpha * z[(size_t)s * HID + j]);
    }
}

extern "C" void kernel_launch(void* const* d_in, const int* in_sizes, int n_in,
                              void* d_out, int out_size, void* d_ws, size_t ws_size,
                              hipStream_t stream) {
    const int*   node_id = (const int*)d_in[0];
    const float* img_h   = (const float*)d_in[1];
    const float* txt_h   = (const float*)d_in[2];
    const int*   src     = (const int*)d_in[3];
    const int*   dst     = (const int*)d_in[4];
    const float* emb     = (const float*)d_in[5];
    const float* W_img   = (const float*)d_in[6];
    const float* iW1     = (const float*)d_in[7];
    const float* ib1     = (const float*)d_in[8];
    const float* iW2     = (const float*)d_in[9];
    const float* ib2     = (const float*)d_in[10];
    const float* iW3     = (const float*)d_in[11];
    const float* ib3     = (const float*)d_in[12];
    const float* W_txt   = (const float*)d_in[13];
    const float* tW1     = (const float*)d_in[14];
    const float* tb1     = (const float*)d_in[15];
    const float* tW2     = (const float*)d_in[16];
    const float* tb2     = (const float*)d_in[17];
    const float* tW3     = (const float*)d_in[18];
    const float* tb3     = (const float*)d_in[19];
    const float* combW   = (const float*)d_in[20];
    const float* combb   = (const float*)d_in[21];
    const float* fcW     = (const float*)d_in[22];
    const float* attn    = (const float*)d_in[23];

    float* ws    = (float*)d_ws;
    float* img_f = ws;                                  // N*HID  (z aliases this)
    float* txt_f = img_f + (size_t)N_NODES * HID;       // N*HID
    float* e_s   = txt_f + (size_t)N_NODES * HID;       // N
    float* e_d   = e_s + N_NODES;                       // N
    float* denom = e_d + N_NODES;                       // N
    float* exbuf = denom + N_NODES;                     // E
    float* z     = img_f;  // safe: node_kernel reads img_f[n] before writing z[n] in-thread

    // B prepack buffers alias exbuf (only live before edge phase writes exbuf):
    // need 2 * IMG_D*HID ushorts = 1 MB  <  E*4 = 3.2 MB
    unsigned short* Bhi = (unsigned short*)exbuf;
    unsigned short* Blo = Bhi + (size_t)IMG_D * HID;

    float* out_f = (float*)d_out;
    hipMemsetAsync(denom, 0, (size_t)N_NODES * sizeof(float), stream);
    hipMemsetAsync(out_f, 0, (size_t)N_NODES * HID * sizeof(float), stream);

    prep_B<<<(IMG_D * HID + 255) / 256, 256, 0, stream>>>(W_img, Bhi, Blo, IMG_D);
    feat_gemm_mfma<IMG_D><<<(N_NODES + 127) / 128, 256, 0, stream>>>(img_h, Bhi, Blo, img_f, N_NODES);
    prep_B<<<(TXT_D * HID + 255) / 256, 256, 0, stream>>>(W_txt, Bhi, Blo, TXT_D);
    feat_gemm_mfma<TXT_D><<<(N_NODES + 127) / 128, 256, 0, stream>>>(txt_h, Bhi, Blo, txt_f, N_NODES);

    node_kernel<<<N_NODES / NPB, 128, 0, stream>>>(node_id, emb, img_f, txt_f,
        iW1, ib1, iW2, ib2, iW3, ib3,
        tW1, tb1, tW2, tb2, tW3, tb3,
        combW, combb, fcW, attn, z, e_s, e_d);

    edge_softmax_pre<<<(N_EDGES + 255) / 256, 256, 0, stream>>>(src, dst, e_s, e_d, exbuf, denom);

    edge_aggregate<<<(N_EDGES + EPB - 1) / EPB, 128, 0, stream>>>(src, dst, exbuf, denom, z, out_f);
}

// Round 3
// 1321.248 us; speedup vs baseline: 1.9552x; 1.2609x over previous
//
#include <hip/hip_runtime.h>
#include <hip/hip_bf16.h>

#define N_NODES 50000
#define N_EDGES 800000
#define HID     128
#define IMG_D   2048
#define TXT_D   768
#define EPB     16   // edges per block in aggregate

typedef short          s16x8 __attribute__((ext_vector_type(8)));
typedef unsigned short u16x8 __attribute__((ext_vector_type(8)));
typedef unsigned short u16x4 __attribute__((ext_vector_type(4)));
typedef float          f32x4 __attribute__((ext_vector_type(4)));

// ---- fp32 -> bf16 (RNE) ----
static __device__ __forceinline__ unsigned short f2bf(float f) {
    unsigned int x = __float_as_uint(f);
    x += 0x7fffu + ((x >> 16) & 1u);
    return (unsigned short)(x >> 16);
}
struct BfPair { unsigned short h, l; };
// split a = hi + lo (both bf16), |a - hi - lo| ~ 2^-17 |a|
static __device__ __forceinline__ BfPair bsplit(float a) {
    BfPair p;
    p.h = f2bf(a);
    float hf = __uint_as_float((unsigned int)p.h << 16);
    p.l = f2bf(a - hf);
    return p;
}

static __device__ __forceinline__ f32x4 mfma16(s16x8 a, s16x8 b, f32x4 c) {
    return __builtin_amdgcn_mfma_f32_16x16x32_bf16(a, b, c, 0, 0, 0);
}

// ---- prepacked weight bases (u16x8 units) ----
#define WB_IMG  0u
#define WB_TXT  32768u
#define WB_IW1  45056u
#define WB_TW1  49152u
#define WB_COMB 53248u
#define WB_IW2  57344u
#define WB_TW2  59392u
#define WB_FC   61440u
#define W_TOTAL_ELEMS 507904

// ---------------- prepack all weights: fp32 [K x 128] -> bf16 hi/lo fragment order ----------------
// Fragment (kf = k/32, nf = col/16): 64 lanes x 8 bf16. lane = 16*(krem/8)+(col%16); slot = krem%8.
__global__ __launch_bounds__(256)
void prep_all(const float* __restrict__ Wimg, const float* __restrict__ Wtxt,
              const float* __restrict__ iW1, const float* __restrict__ tW1,
              const float* __restrict__ combW, const float* __restrict__ iW2,
              const float* __restrict__ tW2, const float* __restrict__ fcW,
              unsigned short* __restrict__ Whi, unsigned short* __restrict__ Wlo) {
    int idx = blockIdx.x * 256 + threadIdx.x;
    if (idx >= W_TOTAL_ELEMS) return;
    const float* S; int li; size_t base;
    if (idx < 262144)      { S = Wimg;  li = idx;          base = 0; }
    else if (idx < 360448) { S = Wtxt;  li = idx - 262144; base = 262144; }
    else if (idx < 393216) { S = iW1;   li = idx - 360448; base = 360448; }
    else if (idx < 425984) { S = tW1;   li = idx - 393216; base = 393216; }
    else if (idx < 458752) { S = combW; li = idx - 425984; base = 425984; }
    else if (idx < 475136) { S = iW2;   li = idx - 458752; base = 458752; }
    else if (idx < 491520) { S = tW2;   li = idx - 475136; base = 475136; }
    else                   { S = fcW;   li = idx - 491520; base = 491520; }
    int k = li >> 7, col = li & 127;
    int kf = k >> 5, kr = k & 31, b = kr >> 3, i = kr & 7;
    int nf = col >> 4, rr = col & 15, l = (b << 4) | rr;
    size_t o = base + ((((size_t)kf * 8 + nf) * 64) + l) * 8 + i;
    BfPair p = bsplit(S[(size_t)k * HID + col]);
    Whi[o] = p.h; Wlo[o] = p.l;
}

// ---------------- shared GEMM helpers ----------------
static __device__ __forceinline__ void zacc(f32x4 acc[4][4]) {
    #pragma unroll
    for (int m = 0; m < 4; ++m)
        #pragma unroll
        for (int n = 0; n < 4; ++n) acc[m][n] = f32x4{0.f, 0.f, 0.f, 0.f};
}

// deposit 4 consecutive-k fp32 values into swizzled hi/lo LDS operand tile [128][128]
static __device__ __forceinline__ void stash4(unsigned short* sHi, unsigned short* sLo,
                                              int r, int k, float4 v) {
    int e = (k & 64) | ((k & 63) ^ ((r & 7) << 3));
    BfPair p0 = bsplit(v.x), p1 = bsplit(v.y), p2 = bsplit(v.z), p3 = bsplit(v.w);
    u16x4 hh = {p0.h, p1.h, p2.h, p3.h}, ll = {p0.l, p1.l, p2.l, p3.l};
    *(u16x4*)&sHi[r * 128 + e] = hh;
    *(u16x4*)&sLo[r * 128 + e] = ll;
}
static __device__ __forceinline__ void stash1(unsigned short* sHi, unsigned short* sLo,
                                              int r, int k, float v) {
    int e = (k & 64) | ((k & 63) ^ ((r & 7) << 3));
    BfPair p = bsplit(v);
    sHi[r * 128 + e] = p.h;
    sLo[r * 128 + e] = p.l;
}

// run 2 BK=64 chunks (K=128 of the operand tile) against prepacked weight at wbase8
static __device__ __forceinline__ void gemm_chunks(
        f32x4 acc[4][4], const unsigned short* sHi, const unsigned short* sLo,
        const unsigned short* __restrict__ Whi, const unsigned short* __restrict__ Wlo,
        size_t wbase8, int kfbase, int lane, int wr, int wc) {
    #pragma unroll
    for (int c = 0; c < 2; ++c)
    #pragma unroll
    for (int ks = 0; ks < 2; ++ks) {
        s16x8 ah[4], al[4], bh[4], bl[4];
        const int kf = kfbase + (c << 1) + ks;
        const int eb = (ks << 5) | ((lane >> 4) << 3);
        #pragma unroll
        for (int m = 0; m < 4; ++m) {
            int r = (wr << 6) + (m << 4) + (lane & 15);
            int e = (c << 6) | (eb ^ ((r & 7) << 3));
            ah[m] = __builtin_bit_cast(s16x8, *(const u16x8*)&sHi[r * 128 + e]);
            al[m] = __builtin_bit_cast(s16x8, *(const u16x8*)&sLo[r * 128 + e]);
        }
        #pragma unroll
        for (int n = 0; n < 4; ++n) {
            size_t fo = wbase8 + ((size_t)kf * 8 + (wc << 2) + n) * 64 + lane;
            bh[n] = __builtin_bit_cast(s16x8, ((const u16x8*)Whi)[fo]);
            bl[n] = __builtin_bit_cast(s16x8, ((const u16x8*)Wlo)[fo]);
        }
        #pragma unroll
        for (int m = 0; m < 4; ++m)
        #pragma unroll
        for (int n = 0; n < 4; ++n) {
            acc[m][n] = mfma16(ah[m], bh[n], acc[m][n]);
            acc[m][n] = mfma16(al[m], bh[n], acc[m][n]);
            acc[m][n] = mfma16(ah[m], bl[n], acc[m][n]);
        }
    }
}

// shuffle-reduce per-row partial dots; red[wc*128+row] gets this wave's 16-lane-group sums
static __device__ __forceinline__ void rowdot_reduce(float vals[16], float* red,
                                                     int lane, int wr, int wc) {
    #pragma unroll
    for (int off = 1; off < 16; off <<= 1)
        #pragma unroll
        for (int t = 0; t < 16; ++t) vals[t] += __shfl_xor(vals[t], off, 64);
    if ((lane & 15) == 0) {
        int g = lane >> 4;
        #pragma unroll
        for (int m = 0; m < 4; ++m)
            #pragma unroll
            for (int jj = 0; jj < 4; ++jj)
                red[wc * 128 + (wr << 6) + (g << 2) + (m << 4) + jj] = vals[(m << 2) + jj];
    }
}

// ---------------- MFMA feature GEMM (unchanged, proven) ----------------
template<int K>
__global__ __launch_bounds__(256, 2)
void feat_gemm_mfma(const float* __restrict__ A,
                    const unsigned short* __restrict__ Bhi,
                    const unsigned short* __restrict__ Blo,
                    float* __restrict__ C, int M) {
    __shared__ __align__(16) unsigned short sAhi[128][64];
    __shared__ __align__(16) unsigned short sAlo[128][64];

    const int tid  = threadIdx.x;
    const int lane = tid & 63;
    const int wid  = tid >> 6;
    const int wr   = wid >> 1;
    const int wc   = wid & 1;
    const int row0 = blockIdx.x * 128;

    f32x4 acc[4][4];
    zacc(acc);

    for (int k0 = 0; k0 < K; k0 += 64) {
        #pragma unroll
        for (int it = 0; it < 8; ++it) {
            int chunk = tid + (it << 8);
            int r  = chunk >> 4;
            int kc = chunk & 15;
            int gr = row0 + r; if (gr >= M) gr = M - 1;
            const float4 av = *(const float4*)&A[(size_t)gr * K + k0 + (kc << 2)];
            BfPair p0 = bsplit(av.x), p1 = bsplit(av.y), p2 = bsplit(av.z), p3 = bsplit(av.w);
            u16x4 h = {p0.h, p1.h, p2.h, p3.h};
            u16x4 l = {p0.l, p1.l, p2.l, p3.l};
            int e = (kc << 2) ^ ((r & 7) << 3);
            *(u16x4*)&sAhi[r][e] = h;
            *(u16x4*)&sAlo[r][e] = l;
        }
        __syncthreads();

        #pragma unroll
        for (int ks = 0; ks < 2; ++ks) {
            s16x8 ah[4], al[4], bh[4], bl[4];
            const int e0 = (ks << 5) | ((lane >> 4) << 3);
            #pragma unroll
            for (int m = 0; m < 4; ++m) {
                int r = (wr << 6) + (m << 4) + (lane & 15);
                int e = e0 ^ ((r & 7) << 3);
                ah[m] = __builtin_bit_cast(s16x8, *(const u16x8*)&sAhi[r][e]);
                al[m] = __builtin_bit_cast(s16x8, *(const u16x8*)&sAlo[r][e]);
            }
            const int kf = (k0 >> 5) + ks;
            #pragma unroll
            for (int n = 0; n < 4; ++n) {
                int nf = (wc << 2) + n;
                size_t fo = ((size_t)kf * 8 + nf) * 64 + lane;
                bh[n] = __builtin_bit_cast(s16x8, ((const u16x8*)Bhi)[fo]);
                bl[n] = __builtin_bit_cast(s16x8, ((const u16x8*)Blo)[fo]);
            }
            #pragma unroll
            for (int m = 0; m < 4; ++m)
                #pragma unroll
                for (int n = 0; n < 4; ++n) {
                    acc[m][n] = mfma16(ah[m], bh[n], acc[m][n]);
                    acc[m][n] = mfma16(al[m], bh[n], acc[m][n]);
                    acc[m][n] = mfma16(ah[m], bl[n], acc[m][n]);
                }
        }
        __syncthreads();
    }

    const int crow = (wr << 6) + ((lane >> 4) << 2);
    const int ccol = (wc << 6) + (lane & 15);
    #pragma unroll
    for (int m = 0; m < 4; ++m)
        #pragma unroll
        for (int n = 0; n < 4; ++n)
            #pragma unroll
            for (int j = 0; j < 4; ++j) {
                int grow = row0 + crow + (m << 4) + j;
                if (grow < M) C[(size_t)grow * HID + ccol + (n << 4)] = acc[m][n][j];
            }
}

// ---------------- fused MFMA node kernel: 128 nodes per block ----------------
// Chain: H1=relu([emb|imgf]@iW1+b1) -> H2=relu(H1@iW2+b2) -> g=sigm(H2@iW3+b3)
//        (same for txt) -> gate=[img_v|txt_v]@combW+cb -> h -> z=h@fcW -> e dots
__global__ __launch_bounds__(256, 2)
void node_mfma(const int* __restrict__ node_id, const float* __restrict__ emb_table,
               const float* __restrict__ img_f_all, const float* __restrict__ txt_f_all,
               const unsigned short* __restrict__ Whi, const unsigned short* __restrict__ Wlo,
               const float* __restrict__ ib1, const float* __restrict__ ib2,
               const float* __restrict__ iW3, const float* __restrict__ ib3,
               const float* __restrict__ tb1, const float* __restrict__ tb2,
               const float* __restrict__ tW3, const float* __restrict__ tb3,
               const float* __restrict__ combb, const float* __restrict__ attn,
               float* __restrict__ z_out, float* __restrict__ e_src, float* __restrict__ e_dst,
               int M) {
    __shared__ __align__(16) unsigned short sHi[128 * 128];   // 32 KB
    __shared__ __align__(16) unsigned short sLo[128 * 128];   // 32 KB
    __shared__ int   sNid[128];
    __shared__ float sGi[128], sGt[128];
    __shared__ float red[4 * 128];

    const int tid = threadIdx.x, lane = tid & 63, wid = tid >> 6;
    const int wr = wid >> 1, wc = wid & 1;
    const int n0 = blockIdx.x * 128;
    const int crow = (wr << 6) + ((lane >> 4) << 2);
    const int ccol = (wc << 6) + (lane & 15);

    if (tid < 128) { int gr = n0 + tid; if (gr >= M) gr = M - 1; sNid[tid] = node_id[gr]; }
    __syncthreads();

    f32x4 acc[4][4];

    // stagers: 16 iters x 256 thr cover 128 rows x 32 float4 (=128 cols)
    auto stage_emb = [&]() {
        #pragma unroll
        for (int it = 0; it < 16; ++it) {
            int chunk = tid + (it << 8);
            int r = chunk >> 5, k = (chunk & 31) << 2;
            float4 v = *(const float4*)&emb_table[(size_t)sNid[r] * HID + k];
            stash4(sHi, sLo, r, k, v);
        }
    };
    auto stage_row = [&](const float* __restrict__ src) {
        #pragma unroll
        for (int it = 0; it < 16; ++it) {
            int chunk = tid + (it << 8);
            int r = chunk >> 5, k = (chunk & 31) << 2;
            int grow = n0 + r; if (grow >= M) grow = M - 1;
            float4 v = *(const float4*)&src[(size_t)grow * HID + k];
            stash4(sHi, sLo, r, k, v);
        }
    };
    auto stage_fused = [&](const float* __restrict__ src, const float* g) {
        #pragma unroll
        for (int it = 0; it < 16; ++it) {
            int chunk = tid + (it << 8);
            int r = chunk >> 5, k = (chunk & 31) << 2;
            int grow = n0 + r; if (grow >= M) grow = M - 1;
            float gg = g[r];
            float4 f = *(const float4*)&src[(size_t)grow * HID + k];
            float4 e = *(const float4*)&emb_table[(size_t)sNid[r] * HID + k];
            float4 v;
            v.x = gg * f.x + (1.f - gg) * e.x;
            v.y = gg * f.y + (1.f - gg) * e.y;
            v.z = gg * f.z + (1.f - gg) * e.z;
            v.w = gg * f.w + (1.f - gg) * e.w;
            stash4(sHi, sLo, r, k, v);
        }
    };
    // gate MLP tail: H1 deposit done by caller; this runs GEMM2 + W3 dot + sigmoid into g[]
    auto gate_tail = [&](size_t wb2, const float* __restrict__ b2,
                         const float* __restrict__ W3, const float* __restrict__ b3,
                         float* g) {
        zacc(acc);
        gemm_chunks(acc, sHi, sLo, Whi, Wlo, wb2, 0, lane, wr, wc);
        float bv[4], wv[4];
        #pragma unroll
        for (int n = 0; n < 4; ++n) { bv[n] = b2[ccol + (n << 4)]; wv[n] = W3[ccol + (n << 4)]; }
        float vals[16];
        #pragma unroll
        for (int m = 0; m < 4; ++m)
            #pragma unroll
            for (int jj = 0; jj < 4; ++jj) {
                float s = 0.f;
                #pragma unroll
                for (int n = 0; n < 4; ++n)
                    s += fmaxf(acc[m][n][jj] + bv[n], 0.f) * wv[n];
                vals[(m << 2) + jj] = s;
            }
        rowdot_reduce(vals, red, lane, wr, wc);
        __syncthreads();                                   // red ready; sOp reads done
        if (tid < 128) g[tid] = 1.f / (1.f + expf(-(red[tid] + red[128 + tid] + b3[0])));
        __syncthreads();                                   // g ready; sOp free
    };
    // one full gate: X=[emb|feat] -> H1 -> gate_tail
    auto gate_mlp = [&](const float* __restrict__ feat, size_t wb1,
                        const float* __restrict__ b1, size_t wb2,
                        const float* __restrict__ b2, const float* __restrict__ W3,
                        const float* __restrict__ b3, float* g) {
        zacc(acc);
        stage_emb();  __syncthreads();
        gemm_chunks(acc, sHi, sLo, Whi, Wlo, wb1, 0, lane, wr, wc);
        __syncthreads();
        stage_row(feat);  __syncthreads();
        gemm_chunks(acc, sHi, sLo, Whi, Wlo, wb1, 4, lane, wr, wc);
        __syncthreads();                                   // before H1 deposit overwrite
        float bv[4];
        #pragma unroll
        for (int n = 0; n < 4; ++n) bv[n] = b1[ccol + (n << 4)];
        #pragma unroll
        for (int m = 0; m < 4; ++m)
            #pragma unroll
            for (int jj = 0; jj < 4; ++jj) {
                int r = crow + (m << 4) + jj;
                #pragma unroll
                for (int n = 0; n < 4; ++n)
                    stash1(sHi, sLo, r, ccol + (n << 4), fmaxf(acc[m][n][jj] + bv[n], 0.f));
            }
        __syncthreads();                                   // H1 ready
        gate_tail(wb2, b2, W3, b3, g);
    };

    gate_mlp(img_f_all, WB_IW1, ib1, WB_IW2, ib2, iW3, ib3, sGi);
    gate_mlp(txt_f_all, WB_TW1, tb1, WB_TW2, tb2, tW3, tb3, sGt);

    // ===== comb GEMM: [img_v | txt_v] @ combW =====
    zacc(acc);
    stage_fused(img_f_all, sGi);  __syncthreads();
    gemm_chunks(acc, sHi, sLo, Whi, Wlo, WB_COMB, 0, lane, wr, wc);
    __syncthreads();
    stage_fused(txt_f_all, sGt);  __syncthreads();
    gemm_chunks(acc, sHi, sLo, Whi, Wlo, WB_COMB, 4, lane, wr, wc);
    __syncthreads();                                       // before h deposit overwrite

    // h = gate*img_v + (1-gate)*txt_v  (recompute img_v/txt_v at C-layout positions)
    {
        float bv[4];
        #pragma unroll
        for (int n = 0; n < 4; ++n) bv[n] = combb[ccol + (n << 4)];
        #pragma unroll
        for (int m = 0; m < 4; ++m)
            #pragma unroll
            for (int jj = 0; jj < 4; ++jj) {
                int r = crow + (m << 4) + jj;
                int grow = n0 + r; if (grow >= M) grow = M - 1;
                float gi = sGi[r], gt = sGt[r];
                size_t ebase = (size_t)sNid[r] * HID;
                #pragma unroll
                for (int n = 0; n < 4; ++n) {
                    int c = ccol + (n << 4);
                    float em = emb_table[ebase + c];
                    float fi = img_f_all[(size_t)grow * HID + c];
                    float ft = txt_f_all[(size_t)grow * HID + c];
                    float iv = gi * fi + (1.f - gi) * em;
                    float tv = gt * ft + (1.f - gt) * em;
                    float gate = acc[m][n][jj] + bv[n];
                    stash1(sHi, sLo, r, c, gate * iv + (1.f - gate) * tv);
                }
            }
    }
    __syncthreads();                                       // h ready

    // ===== fc GEMM + z store + attn dots =====
    zacc(acc);
    gemm_chunks(acc, sHi, sLo, Whi, Wlo, WB_FC, 0, lane, wr, wc);
    {
        float a1v[4], a2v[4];
        #pragma unroll
        for (int n = 0; n < 4; ++n) {
            a1v[n] = attn[ccol + (n << 4)];
            a2v[n] = attn[HID + ccol + (n << 4)];
        }
        float v1[16], v2[16];
        #pragma unroll
        for (int m = 0; m < 4; ++m)
            #pragma unroll
            for (int jj = 0; jj < 4; ++jj) {
                int grow = n0 + crow + (m << 4) + jj;
                float s1 = 0.f, s2 = 0.f;
                #pragma unroll
                for (int n = 0; n < 4; ++n) {
                    float zv = acc[m][n][jj];
                    if (grow < M) z_out[(size_t)grow * HID + ccol + (n << 4)] = zv;
                    s1 += zv * a1v[n];
                    s2 += zv * a2v[n];
                }
                v1[(m << 2) + jj] = s1;
                v2[(m << 2) + jj] = s2;
            }
        rowdot_reduce(v1, red, lane, wr, wc);
        rowdot_reduce(v2, red + 256, lane, wr, wc);
    }
    __syncthreads();
    if (tid < 128) {
        int gr = n0 + tid;
        if (gr < M) {
            e_src[gr] = red[tid] + red[128 + tid];
            e_dst[gr] = red[256 + tid] + red[384 + tid];
        }
    }
}

// ---------------- edge phase 1: exp(e) + denom ----------------
__global__ __launch_bounds__(256)
void edge_softmax_pre(const int* __restrict__ src, const int* __restrict__ dst,
                      const float* __restrict__ e_src, const float* __restrict__ e_dst,
                      float* __restrict__ exbuf, float* __restrict__ denom) {
    int k = blockIdx.x * 256 + threadIdx.x;
    if (k >= N_EDGES) return;
    float e = e_src[src[k]] + e_dst[dst[k]];
    e = (e >= 0.f) ? e : 0.01f * e;   // leaky_relu(0.01)
    float ex = expf(e);
    exbuf[k] = ex;
    atomicAdd(&denom[dst[k]], ex);
}

// ---------------- edge phase 2: weighted aggregation ----------------
__global__ __launch_bounds__(128)
void edge_aggregate(const int* __restrict__ src, const int* __restrict__ dst,
                    const float* __restrict__ exbuf, const float* __restrict__ denom,
                    const float* __restrict__ z, float* __restrict__ hout) {
    int j = threadIdx.x;
    int base = blockIdx.x * EPB;
    int end = base + EPB;
    if (end > N_EDGES) end = N_EDGES;
    for (int k = base; k < end; ++k) {
        int d = dst[k], s = src[k];
        float alpha = exbuf[k] / fmaxf(denom[d], 1e-20f);
        atomicAdd(&hout[(size_t)d * HID + j], alpha * z[(size_t)s * HID + j]);
    }
}

extern "C" void kernel_launch(void* const* d_in, const int* in_sizes, int n_in,
                              void* d_out, int out_size, void* d_ws, size_t ws_size,
                              hipStream_t stream) {
    const int*   node_id = (const int*)d_in[0];
    const float* img_h   = (const float*)d_in[1];
    const float* txt_h   = (const float*)d_in[2];
    const int*   src     = (const int*)d_in[3];
    const int*   dst     = (const int*)d_in[4];
    const float* emb     = (const float*)d_in[5];
    const float* W_img   = (const float*)d_in[6];
    const float* iW1     = (const float*)d_in[7];
    const float* ib1     = (const float*)d_in[8];
    const float* iW2     = (const float*)d_in[9];
    const float* ib2     = (const float*)d_in[10];
    const float* iW3     = (const float*)d_in[11];
    const float* ib3     = (const float*)d_in[12];
    const float* W_txt   = (const float*)d_in[13];
    const float* tW1     = (const float*)d_in[14];
    const float* tb1     = (const float*)d_in[15];
    const float* tW2     = (const float*)d_in[16];
    const float* tb2     = (const float*)d_in[17];
    const float* tW3     = (const float*)d_in[18];
    const float* tb3     = (const float*)d_in[19];
    const float* combW   = (const float*)d_in[20];
    const float* combb   = (const float*)d_in[21];
    const float* fcW     = (const float*)d_in[22];
    const float* attn    = (const float*)d_in[23];

    float* ws    = (float*)d_ws;
    float* img_f = ws;                                  // N*HID  (z aliases this)
    float* txt_f = img_f + (size_t)N_NODES * HID;       // N*HID
    float* e_s   = txt_f + (size_t)N_NODES * HID;       // N
    float* e_d   = e_s + N_NODES;                       // N
    float* denom = e_d + N_NODES;                       // N
    float* exbuf = denom + N_NODES;                     // E
    float* z     = img_f;  // node_mfma reads img_f before writing z rows (own tile only)

    // prepacked weights alias exbuf (dead once edge_softmax_pre writes exbuf):
    // 2 * 507904 u16 = 2.03 MB < E*4 = 3.2 MB
    unsigned short* Whi = (unsigned short*)exbuf;
    unsigned short* Wlo = Whi + W_TOTAL_ELEMS;

    float* out_f = (float*)d_out;
    hipMemsetAsync(denom, 0, (size_t)N_NODES * sizeof(float), stream);
    hipMemsetAsync(out_f, 0, (size_t)N_NODES * HID * sizeof(float), stream);

    prep_all<<<W_TOTAL_ELEMS / 256, 256, 0, stream>>>(W_img, W_txt, iW1, tW1, combW,
                                                      iW2, tW2, fcW, Whi, Wlo);

    feat_gemm_mfma<IMG_D><<<(N_NODES + 127) / 128, 256, 0, stream>>>(
        img_h, Whi + WB_IMG * 8, Wlo + WB_IMG * 8, img_f, N_NODES);
    feat_gemm_mfma<TXT_D><<<(N_NODES + 127) / 128, 256, 0, stream>>>(
        txt_h, Whi + WB_TXT * 8, Wlo + WB_TXT * 8, txt_f, N_NODES);

    node_mfma<<<(N_NODES + 127) / 128, 256, 0, stream>>>(
        node_id, emb, img_f, txt_f, Whi, Wlo,
        ib1, ib2, iW3, ib3, tb1, tb2, tW3, tb3,
        combb, attn, z, e_s, e_d, N_NODES);

    edge_softmax_pre<<<(N_EDGES + 255) / 256, 256, 0, stream>>>(src, dst, e_s, e_d, exbuf, denom);

    edge_aggregate<<<(N_EDGES + EPB - 1) / EPB, 128, 0, stream>>>(src, dst, exbuf, denom, z, out_f);
}

// Round 4
// 1191.480 us; speedup vs baseline: 2.1681x; 1.1089x over previous
//
#include <hip/hip_runtime.h>
#include <hip/hip_bf16.h>

#define N_NODES 50000
#define N_EDGES 800000
#define HID     128
#define IMG_D   2048
#define TXT_D   768

typedef short          s16x8 __attribute__((ext_vector_type(8)));
typedef unsigned short u16x8 __attribute__((ext_vector_type(8)));
typedef unsigned short u16x4 __attribute__((ext_vector_type(4)));
typedef float          f32x4 __attribute__((ext_vector_type(4)));

// ---- fp32 -> bf16 (RNE) ----
static __device__ __forceinline__ unsigned short f2bf(float f) {
    unsigned int x = __float_as_uint(f);
    x += 0x7fffu + ((x >> 16) & 1u);
    return (unsigned short)(x >> 16);
}
struct BfPair { unsigned short h, l; };
// split a = hi + lo (both bf16), |a - hi - lo| ~ 2^-17 |a|
static __device__ __forceinline__ BfPair bsplit(float a) {
    BfPair p;
    p.h = f2bf(a);
    float hf = __uint_as_float((unsigned int)p.h << 16);
    p.l = f2bf(a - hf);
    return p;
}

static __device__ __forceinline__ f32x4 mfma16(s16x8 a, s16x8 b, f32x4 c) {
    return __builtin_amdgcn_mfma_f32_16x16x32_bf16(a, b, c, 0, 0, 0);
}

// ---- prepacked weight bases (u16x8 units) ----
#define WB_IMG  0u
#define WB_TXT  32768u
#define WB_IW1  45056u
#define WB_TW1  49152u
#define WB_COMB 53248u
#define WB_IW2  57344u
#define WB_TW2  59392u
#define WB_FC   61440u
#define W_TOTAL_ELEMS 507904

// ---------------- prepack all weights: fp32 [K x 128] -> bf16 hi/lo fragment order ----------------
__global__ __launch_bounds__(256)
void prep_all(const float* __restrict__ Wimg, const float* __restrict__ Wtxt,
              const float* __restrict__ iW1, const float* __restrict__ tW1,
              const float* __restrict__ combW, const float* __restrict__ iW2,
              const float* __restrict__ tW2, const float* __restrict__ fcW,
              unsigned short* __restrict__ Whi, unsigned short* __restrict__ Wlo) {
    int idx = blockIdx.x * 256 + threadIdx.x;
    if (idx >= W_TOTAL_ELEMS) return;
    const float* S; int li; size_t base;
    if (idx < 262144)      { S = Wimg;  li = idx;          base = 0; }
    else if (idx < 360448) { S = Wtxt;  li = idx - 262144; base = 262144; }
    else if (idx < 393216) { S = iW1;   li = idx - 360448; base = 360448; }
    else if (idx < 425984) { S = tW1;   li = idx - 393216; base = 393216; }
    else if (idx < 458752) { S = combW; li = idx - 425984; base = 425984; }
    else if (idx < 475136) { S = iW2;   li = idx - 458752; base = 458752; }
    else if (idx < 491520) { S = tW2;   li = idx - 475136; base = 475136; }
    else                   { S = fcW;   li = idx - 491520; base = 491520; }
    int k = li >> 7, col = li & 127;
    int kf = k >> 5, kr = k & 31, b = kr >> 3, i = kr & 7;
    int nf = col >> 4, rr = col & 15, l = (b << 4) | rr;
    size_t o = base + ((((size_t)kf * 8 + nf) * 64) + l) * 8 + i;
    BfPair p = bsplit(S[(size_t)k * HID + col]);
    Whi[o] = p.h; Wlo[o] = p.l;
}

// ---------------- shared GEMM helpers ----------------
static __device__ __forceinline__ void zacc(f32x4 acc[4][4]) {
    #pragma unroll
    for (int m = 0; m < 4; ++m)
        #pragma unroll
        for (int n = 0; n < 4; ++n) acc[m][n] = f32x4{0.f, 0.f, 0.f, 0.f};
}

static __device__ __forceinline__ void stash4(unsigned short* sHi, unsigned short* sLo,
                                              int r, int k, float4 v) {
    int e = (k & 64) | ((k & 63) ^ ((r & 7) << 3));
    BfPair p0 = bsplit(v.x), p1 = bsplit(v.y), p2 = bsplit(v.z), p3 = bsplit(v.w);
    u16x4 hh = {p0.h, p1.h, p2.h, p3.h}, ll = {p0.l, p1.l, p2.l, p3.l};
    *(u16x4*)&sHi[r * 128 + e] = hh;
    *(u16x4*)&sLo[r * 128 + e] = ll;
}
static __device__ __forceinline__ void stash1(unsigned short* sHi, unsigned short* sLo,
                                              int r, int k, float v) {
    int e = (k & 64) | ((k & 63) ^ ((r & 7) << 3));
    BfPair p = bsplit(v);
    sHi[r * 128 + e] = p.h;
    sLo[r * 128 + e] = p.l;
}

static __device__ __forceinline__ void gemm_chunks(
        f32x4 acc[4][4], const unsigned short* sHi, const unsigned short* sLo,
        const unsigned short* __restrict__ Whi, const unsigned short* __restrict__ Wlo,
        size_t wbase8, int kfbase, int lane, int wr, int wc) {
    #pragma unroll
    for (int c = 0; c < 2; ++c)
    #pragma unroll
    for (int ks = 0; ks < 2; ++ks) {
        s16x8 ah[4], al[4], bh[4], bl[4];
        const int kf = kfbase + (c << 1) + ks;
        const int eb = (ks << 5) | ((lane >> 4) << 3);
        #pragma unroll
        for (int m = 0; m < 4; ++m) {
            int r = (wr << 6) + (m << 4) + (lane & 15);
            int e = (c << 6) | (eb ^ ((r & 7) << 3));
            ah[m] = __builtin_bit_cast(s16x8, *(const u16x8*)&sHi[r * 128 + e]);
            al[m] = __builtin_bit_cast(s16x8, *(const u16x8*)&sLo[r * 128 + e]);
        }
        #pragma unroll
        for (int n = 0; n < 4; ++n) {
            size_t fo = wbase8 + ((size_t)kf * 8 + (wc << 2) + n) * 64 + lane;
            bh[n] = __builtin_bit_cast(s16x8, ((const u16x8*)Whi)[fo]);
            bl[n] = __builtin_bit_cast(s16x8, ((const u16x8*)Wlo)[fo]);
        }
        #pragma unroll
        for (int m = 0; m < 4; ++m)
        #pragma unroll
        for (int n = 0; n < 4; ++n) {
            acc[m][n] = mfma16(ah[m], bh[n], acc[m][n]);
            acc[m][n] = mfma16(al[m], bh[n], acc[m][n]);
            acc[m][n] = mfma16(ah[m], bl[n], acc[m][n]);
        }
    }
}

static __device__ __forceinline__ void rowdot_reduce(float vals[16], float* red,
                                                     int lane, int wr, int wc) {
    #pragma unroll
    for (int off = 1; off < 16; off <<= 1)
        #pragma unroll
        for (int t = 0; t < 16; ++t) vals[t] += __shfl_xor(vals[t], off, 64);
    if ((lane & 15) == 0) {
        int g = lane >> 4;
        #pragma unroll
        for (int m = 0; m < 4; ++m)
            #pragma unroll
            for (int jj = 0; jj < 4; ++jj)
                red[wc * 128 + (wr << 6) + (g << 2) + (m << 4) + jj] = vals[(m << 2) + jj];
    }
}

// ---------------- MFMA feature GEMM (proven) ----------------
template<int K>
__global__ __launch_bounds__(256, 2)
void feat_gemm_mfma(const float* __restrict__ A,
                    const unsigned short* __restrict__ Bhi,
                    const unsigned short* __restrict__ Blo,
                    float* __restrict__ C, int M) {
    __shared__ __align__(16) unsigned short sAhi[128][64];
    __shared__ __align__(16) unsigned short sAlo[128][64];

    const int tid  = threadIdx.x;
    const int lane = tid & 63;
    const int wid  = tid >> 6;
    const int wr   = wid >> 1;
    const int wc   = wid & 1;
    const int row0 = blockIdx.x * 128;

    f32x4 acc[4][4];
    zacc(acc);

    for (int k0 = 0; k0 < K; k0 += 64) {
        #pragma unroll
        for (int it = 0; it < 8; ++it) {
            int chunk = tid + (it << 8);
            int r  = chunk >> 4;
            int kc = chunk & 15;
            int gr = row0 + r; if (gr >= M) gr = M - 1;
            const float4 av = *(const float4*)&A[(size_t)gr * K + k0 + (kc << 2)];
            BfPair p0 = bsplit(av.x), p1 = bsplit(av.y), p2 = bsplit(av.z), p3 = bsplit(av.w);
            u16x4 h = {p0.h, p1.h, p2.h, p3.h};
            u16x4 l = {p0.l, p1.l, p2.l, p3.l};
            int e = (kc << 2) ^ ((r & 7) << 3);
            *(u16x4*)&sAhi[r][e] = h;
            *(u16x4*)&sAlo[r][e] = l;
        }
        __syncthreads();

        #pragma unroll
        for (int ks = 0; ks < 2; ++ks) {
            s16x8 ah[4], al[4], bh[4], bl[4];
            const int e0 = (ks << 5) | ((lane >> 4) << 3);
            #pragma unroll
            for (int m = 0; m < 4; ++m) {
                int r = (wr << 6) + (m << 4) + (lane & 15);
                int e = e0 ^ ((r & 7) << 3);
                ah[m] = __builtin_bit_cast(s16x8, *(const u16x8*)&sAhi[r][e]);
                al[m] = __builtin_bit_cast(s16x8, *(const u16x8*)&sAlo[r][e]);
            }
            const int kf = (k0 >> 5) + ks;
            #pragma unroll
            for (int n = 0; n < 4; ++n) {
                int nf = (wc << 2) + n;
                size_t fo = ((size_t)kf * 8 + nf) * 64 + lane;
                bh[n] = __builtin_bit_cast(s16x8, ((const u16x8*)Bhi)[fo]);
                bl[n] = __builtin_bit_cast(s16x8, ((const u16x8*)Blo)[fo]);
            }
            #pragma unroll
            for (int m = 0; m < 4; ++m)
                #pragma unroll
                for (int n = 0; n < 4; ++n) {
                    acc[m][n] = mfma16(ah[m], bh[n], acc[m][n]);
                    acc[m][n] = mfma16(al[m], bh[n], acc[m][n]);
                    acc[m][n] = mfma16(ah[m], bl[n], acc[m][n]);
                }
        }
        __syncthreads();
    }

    const int crow = (wr << 6) + ((lane >> 4) << 2);
    const int ccol = (wc << 6) + (lane & 15);
    #pragma unroll
    for (int m = 0; m < 4; ++m)
        #pragma unroll
        for (int n = 0; n < 4; ++n)
            #pragma unroll
            for (int j = 0; j < 4; ++j) {
                int grow = row0 + crow + (m << 4) + j;
                if (grow < M) C[(size_t)grow * HID + ccol + (n << 4)] = acc[m][n][j];
            }
}

// ---------------- fused MFMA node kernel: 128 nodes per block (proven) ----------------
__global__ __launch_bounds__(256, 2)
void node_mfma(const int* __restrict__ node_id, const float* __restrict__ emb_table,
               const float* __restrict__ img_f_all, const float* __restrict__ txt_f_all,
               const unsigned short* __restrict__ Whi, const unsigned short* __restrict__ Wlo,
               const float* __restrict__ ib1, const float* __restrict__ ib2,
               const float* __restrict__ iW3, const float* __restrict__ ib3,
               const float* __restrict__ tb1, const float* __restrict__ tb2,
               const float* __restrict__ tW3, const float* __restrict__ tb3,
               const float* __restrict__ combb, const float* __restrict__ attn,
               float* __restrict__ z_out, float* __restrict__ e_src, float* __restrict__ e_dst,
               int M) {
    __shared__ __align__(16) unsigned short sHi[128 * 128];   // 32 KB
    __shared__ __align__(16) unsigned short sLo[128 * 128];   // 32 KB
    __shared__ int   sNid[128];
    __shared__ float sGi[128], sGt[128];
    __shared__ float red[4 * 128];

    const int tid = threadIdx.x, lane = tid & 63, wid = tid >> 6;
    const int wr = wid >> 1, wc = wid & 1;
    const int n0 = blockIdx.x * 128;
    const int crow = (wr << 6) + ((lane >> 4) << 2);
    const int ccol = (wc << 6) + (lane & 15);

    if (tid < 128) { int gr = n0 + tid; if (gr >= M) gr = M - 1; sNid[tid] = node_id[gr]; }
    __syncthreads();

    f32x4 acc[4][4];

    auto stage_emb = [&]() {
        #pragma unroll
        for (int it = 0; it < 16; ++it) {
            int chunk = tid + (it << 8);
            int r = chunk >> 5, k = (chunk & 31) << 2;
            float4 v = *(const float4*)&emb_table[(size_t)sNid[r] * HID + k];
            stash4(sHi, sLo, r, k, v);
        }
    };
    auto stage_row = [&](const float* __restrict__ src) {
        #pragma unroll
        for (int it = 0; it < 16; ++it) {
            int chunk = tid + (it << 8);
            int r = chunk >> 5, k = (chunk & 31) << 2;
            int grow = n0 + r; if (grow >= M) grow = M - 1;
            float4 v = *(const float4*)&src[(size_t)grow * HID + k];
            stash4(sHi, sLo, r, k, v);
        }
    };
    auto stage_fused = [&](const float* __restrict__ src, const float* g) {
        #pragma unroll
        for (int it = 0; it < 16; ++it) {
            int chunk = tid + (it << 8);
            int r = chunk >> 5, k = (chunk & 31) << 2;
            int grow = n0 + r; if (grow >= M) grow = M - 1;
            float gg = g[r];
            float4 f = *(const float4*)&src[(size_t)grow * HID + k];
            float4 e = *(const float4*)&emb_table[(size_t)sNid[r] * HID + k];
            float4 v;
            v.x = gg * f.x + (1.f - gg) * e.x;
            v.y = gg * f.y + (1.f - gg) * e.y;
            v.z = gg * f.z + (1.f - gg) * e.z;
            v.w = gg * f.w + (1.f - gg) * e.w;
            stash4(sHi, sLo, r, k, v);
        }
    };
    auto gate_tail = [&](size_t wb2, const float* __restrict__ b2,
                         const float* __restrict__ W3, const float* __restrict__ b3,
                         float* g) {
        zacc(acc);
        gemm_chunks(acc, sHi, sLo, Whi, Wlo, wb2, 0, lane, wr, wc);
        float bv[4], wv[4];
        #pragma unroll
        for (int n = 0; n < 4; ++n) { bv[n] = b2[ccol + (n << 4)]; wv[n] = W3[ccol + (n << 4)]; }
        float vals[16];
        #pragma unroll
        for (int m = 0; m < 4; ++m)
            #pragma unroll
            for (int jj = 0; jj < 4; ++jj) {
                float s = 0.f;
                #pragma unroll
                for (int n = 0; n < 4; ++n)
                    s += fmaxf(acc[m][n][jj] + bv[n], 0.f) * wv[n];
                vals[(m << 2) + jj] = s;
            }
        rowdot_reduce(vals, red, lane, wr, wc);
        __syncthreads();
        if (tid < 128) g[tid] = 1.f / (1.f + expf(-(red[tid] + red[128 + tid] + b3[0])));
        __syncthreads();
    };
    auto gate_mlp = [&](const float* __restrict__ feat, size_t wb1,
                        const float* __restrict__ b1, size_t wb2,
                        const float* __restrict__ b2, const float* __restrict__ W3,
                        const float* __restrict__ b3, float* g) {
        zacc(acc);
        stage_emb();  __syncthreads();
        gemm_chunks(acc, sHi, sLo, Whi, Wlo, wb1, 0, lane, wr, wc);
        __syncthreads();
        stage_row(feat);  __syncthreads();
        gemm_chunks(acc, sHi, sLo, Whi, Wlo, wb1, 4, lane, wr, wc);
        __syncthreads();
        float bv[4];
        #pragma unroll
        for (int n = 0; n < 4; ++n) bv[n] = b1[ccol + (n << 4)];
        #pragma unroll
        for (int m = 0; m < 4; ++m)
            #pragma unroll
            for (int jj = 0; jj < 4; ++jj) {
                int r = crow + (m << 4) + jj;
                #pragma unroll
                for (int n = 0; n < 4; ++n)
                    stash1(sHi, sLo, r, ccol + (n << 4), fmaxf(acc[m][n][jj] + bv[n], 0.f));
            }
        __syncthreads();
        gate_tail(wb2, b2, W3, b3, g);
    };

    gate_mlp(img_f_all, WB_IW1, ib1, WB_IW2, ib2, iW3, ib3, sGi);
    gate_mlp(txt_f_all, WB_TW1, tb1, WB_TW2, tb2, tW3, tb3, sGt);

    // ===== comb GEMM =====
    zacc(acc);
    stage_fused(img_f_all, sGi);  __syncthreads();
    gemm_chunks(acc, sHi, sLo, Whi, Wlo, WB_COMB, 0, lane, wr, wc);
    __syncthreads();
    stage_fused(txt_f_all, sGt);  __syncthreads();
    gemm_chunks(acc, sHi, sLo, Whi, Wlo, WB_COMB, 4, lane, wr, wc);
    __syncthreads();

    {
        float bv[4];
        #pragma unroll
        for (int n = 0; n < 4; ++n) bv[n] = combb[ccol + (n << 4)];
        #pragma unroll
        for (int m = 0; m < 4; ++m)
            #pragma unroll
            for (int jj = 0; jj < 4; ++jj) {
                int r = crow + (m << 4) + jj;
                int grow = n0 + r; if (grow >= M) grow = M - 1;
                float gi = sGi[r], gt = sGt[r];
                size_t ebase = (size_t)sNid[r] * HID;
                #pragma unroll
                for (int n = 0; n < 4; ++n) {
                    int c = ccol + (n << 4);
                    float em = emb_table[ebase + c];
                    float fi = img_f_all[(size_t)grow * HID + c];
                    float ft = txt_f_all[(size_t)grow * HID + c];
                    float iv = gi * fi + (1.f - gi) * em;
                    float tv = gt * ft + (1.f - gt) * em;
                    float gate = acc[m][n][jj] + bv[n];
                    stash1(sHi, sLo, r, c, gate * iv + (1.f - gate) * tv);
                }
            }
    }
    __syncthreads();

    // ===== fc GEMM + z store + attn dots =====
    zacc(acc);
    gemm_chunks(acc, sHi, sLo, Whi, Wlo, WB_FC, 0, lane, wr, wc);
    {
        float a1v[4], a2v[4];
        #pragma unroll
        for (int n = 0; n < 4; ++n) {
            a1v[n] = attn[ccol + (n << 4)];
            a2v[n] = attn[HID + ccol + (n << 4)];
        }
        float v1[16], v2[16];
        #pragma unroll
        for (int m = 0; m < 4; ++m)
            #pragma unroll
            for (int jj = 0; jj < 4; ++jj) {
                int grow = n0 + crow + (m << 4) + jj;
                float s1 = 0.f, s2 = 0.f;
                #pragma unroll
                for (int n = 0; n < 4; ++n) {
                    float zv = acc[m][n][jj];
                    if (grow < M) z_out[(size_t)grow * HID + ccol + (n << 4)] = zv;
                    s1 += zv * a1v[n];
                    s2 += zv * a2v[n];
                }
                v1[(m << 2) + jj] = s1;
                v2[(m << 2) + jj] = s2;
            }
        rowdot_reduce(v1, red, lane, wr, wc);
        rowdot_reduce(v2, red + 256, lane, wr, wc);
    }
    __syncthreads();
    if (tid < 128) {
        int gr = n0 + tid;
        if (gr < M) {
            e_src[gr] = red[tid] + red[128 + tid];
            e_dst[gr] = red[256 + tid] + red[384 + tid];
        }
    }
}

// ---------------- CSR build: histogram -> scan -> scatter ----------------
__global__ __launch_bounds__(256)
void edge_hist(const int* __restrict__ dst, int* __restrict__ cnt) {
    int k = blockIdx.x * 256 + threadIdx.x;
    if (k < N_EDGES) atomicAdd(&cnt[dst[k]], 1);
}

// single-block in-place exclusive scan of cnt[0..N_NODES)
__global__ __launch_bounds__(1024)
void scan_offsets(int* __restrict__ cnt) {
    __shared__ int part[1024];
    int tid = threadIdx.x;
    const int CH = (N_NODES + 1023) / 1024;   // 49
    int base = tid * CH;
    int lim = base + CH; if (lim > N_NODES) lim = N_NODES;
    int sum = 0;
    for (int i = base; i < lim; ++i) sum += cnt[i];
    part[tid] = sum;
    __syncthreads();
    for (int off = 1; off < 1024; off <<= 1) {
        int v = (tid >= off) ? part[tid - off] : 0;
        __syncthreads();
        part[tid] += v;
        __syncthreads();
    }
    int run = part[tid] - sum;   // exclusive prefix of this chunk
    for (int i = base; i < lim; ++i) { int c = cnt[i]; cnt[i] = run; run += c; }
}

// destructive scatter: offs becomes INCLUSIVE end after this kernel
__global__ __launch_bounds__(256)
void edge_scatter(const int* __restrict__ src, const int* __restrict__ dst,
                  int* __restrict__ offs, int* __restrict__ bucket) {
    int k = blockIdx.x * 256 + threadIdx.x;
    if (k >= N_EDGES) return;
    int pos = atomicAdd(&offs[dst[k]], 1);
    bucket[pos] = src[k];
}

// ---------------- gather aggregation: one wave per dst row, write once ----------------
__global__ __launch_bounds__(256)
void edge_aggregate_csr(const int* __restrict__ bucket, const int* __restrict__ offs,
                        const float* __restrict__ e_src, const float* __restrict__ e_dst,
                        const float* __restrict__ z, float* __restrict__ hout) {
    int d = blockIdx.x * 4 + (threadIdx.x >> 6);
    if (d >= N_NODES) return;
    int lane = threadIdx.x & 63;
    int start = (d == 0) ? 0 : offs[d - 1];
    int end = offs[d];
    float edv = e_dst[d];
    float ax = 0.f, ay = 0.f, S = 0.f;
    for (int k = start; k < end; ++k) {
        int s = bucket[k];
        float e = e_src[s] + edv;
        e = (e >= 0.f) ? e : 0.01f * e;   // leaky_relu(0.01)
        float ex = expf(e);               // shift-free: e is O(0.1)
        S += ex;
        const float2 zv = *(const float2*)&z[(size_t)s * HID + (lane << 1)];
        ax += ex * zv.x;
        ay += ex * zv.y;
    }
    float inv = 1.f / fmaxf(S, 1e-20f);
    float2 o; o.x = ax * inv; o.y = ay * inv;
    *(float2*)&hout[(size_t)d * HID + (lane << 1)] = o;
}

extern "C" void kernel_launch(void* const* d_in, const int* in_sizes, int n_in,
                              void* d_out, int out_size, void* d_ws, size_t ws_size,
                              hipStream_t stream) {
    const int*   node_id = (const int*)d_in[0];
    const float* img_h   = (const float*)d_in[1];
    const float* txt_h   = (const float*)d_in[2];
    const int*   src     = (const int*)d_in[3];
    const int*   dst     = (const int*)d_in[4];
    const float* emb     = (const float*)d_in[5];
    const float* W_img   = (const float*)d_in[6];
    const float* iW1     = (const float*)d_in[7];
    const float* ib1     = (const float*)d_in[8];
    const float* iW2     = (const float*)d_in[9];
    const float* ib2     = (const float*)d_in[10];
    const float* iW3     = (const float*)d_in[11];
    const float* ib3     = (const float*)d_in[12];
    const float* W_txt   = (const float*)d_in[13];
    const float* tW1     = (const float*)d_in[14];
    const float* tb1     = (const float*)d_in[15];
    const float* tW2     = (const float*)d_in[16];
    const float* tb2     = (const float*)d_in[17];
    const float* tW3     = (const float*)d_in[18];
    const float* tb3     = (const float*)d_in[19];
    const float* combW   = (const float*)d_in[20];
    const float* combb   = (const float*)d_in[21];
    const float* fcW     = (const float*)d_in[22];
    const float* attn    = (const float*)d_in[23];

    float* ws    = (float*)d_ws;
    float* img_f = ws;                                  // N*HID  (z aliases this)
    float* txt_f = img_f + (size_t)N_NODES * HID;       // N*HID
    float* e_s   = txt_f + (size_t)N_NODES * HID;       // N
    float* e_d   = e_s + N_NODES;                       // N
    int*   cnt   = (int*)(e_d + N_NODES);               // N (count -> offsets -> inclusive ends)
    int*   bucket= cnt + N_NODES;                       // E (src ids grouped by dst)
    float* z     = img_f;  // node_mfma reads img_f before writing z rows (own tile only)

    // prepacked weights alias bucket region (bucket written only after node_mfma):
    // 2 * 507904 u16 = 2.03 MB < E*4 = 3.2 MB
    unsigned short* Whi = (unsigned short*)bucket;
    unsigned short* Wlo = Whi + W_TOTAL_ELEMS;

    float* out_f = (float*)d_out;
    hipMemsetAsync(cnt, 0, (size_t)N_NODES * sizeof(int), stream);

    prep_all<<<W_TOTAL_ELEMS / 256, 256, 0, stream>>>(W_img, W_txt, iW1, tW1, combW,
                                                      iW2, tW2, fcW, Whi, Wlo);
    edge_hist<<<(N_EDGES + 255) / 256, 256, 0, stream>>>(dst, cnt);
    scan_offsets<<<1, 1024, 0, stream>>>(cnt);

    feat_gemm_mfma<IMG_D><<<(N_NODES + 127) / 128, 256, 0, stream>>>(
        img_h, Whi + WB_IMG * 8, Wlo + WB_IMG * 8, img_f, N_NODES);
    feat_gemm_mfma<TXT_D><<<(N_NODES + 127) / 128, 256, 0, stream>>>(
        txt_h, Whi + WB_TXT * 8, Wlo + WB_TXT * 8, txt_f, N_NODES);

    node_mfma<<<(N_NODES + 127) / 128, 256, 0, stream>>>(
        node_id, emb, img_f, txt_f, Whi, Wlo,
        ib1, ib2, iW3, ib3, tb1, tb2, tW3, tb3,
        combb, attn, z, e_s, e_d, N_NODES);

    // weights dead from here; bucket may overwrite them
    edge_scatter<<<(N_EDGES + 255) / 256, 256, 0, stream>>>(src, dst, cnt, bucket);

    edge_aggregate_csr<<<(N_NODES + 3) / 4, 256, 0, stream>>>(bucket, cnt, e_s, e_d, z, out_f);
}